// Round 6
// baseline (212.480 us; speedup 1.0000x reference)
//
#include <hip/hip_runtime.h>
#include <math.h>

// loss = mean_b[ 0.5*nrmse(o1,t1) + 0.25*nrmse(o2,t2) + 0.25*nrmse(o3,t3) ]
// B=4096 rows, N=2048 fp32. 201.3 MB in, 4 B out. Roofline ~32 us @6.3 TB/s.
//
// R1: VGPR=32, compiler-serialized loads -> 74 us (2.8 TB/s effective).
// R2: source batch-load reverted by scheduler (VGPR 32, same 74).
// R3: asm burst crashed (missing early-clobber on outputs).
// R5: asm burst + "=&v" ran correctly -> 71 us. Peak-MLP theory FALSIFIED:
//     one-shot burst->drain->compute->exit waves have low in-flight DUTY
//     CYCLE; proven-fast kernels (m13 copy 6.3 TB/s, m146 row-reduce
//     4.9 TB/s) are persistent loops with continuous issue.
// R6: persistent pipelined waves. 768 blocks (3/CU, tail-free), 3072 waves,
//     4 tasks/wave, depth-2 double-buffer, counted s_waitcnt vmcnt(16)
//     (never 0 until last task) + sched_barrier(0) per rule 18.
constexpr int N_ELEM = 2048;
constexpr int BATCH  = 4096;
constexpr int BLOCK  = 256;                 // 4 waves/block
constexpr int TASKS  = 3 * BATCH;           // 12288 (pair,row) tasks
constexpr int GRID1  = 768;                 // 3 blocks/CU resident, one round
constexpr int WAVES  = GRID1 * (BLOCK/64);  // 3072 waves, 4 tasks/wave exactly
static_assert(TASKS % WAVES == 0, "tasks must divide evenly");

typedef float f32x4 __attribute__((ext_vector_type(4)));

// 16 coalesced dwordx4 loads (8 KB o + 8 KB t for one row), NO waitcnt:
// completion is claimed later via counted vmcnt. "=&v" early-clobber is
// required (returns race the address inputs otherwise — R3 lesson).
#define DECL_SET(P) f32x4 P##o0,P##o1,P##o2,P##o3,P##o4,P##o5,P##o6,P##o7, \
                          P##t0,P##t1,P##t2,P##t3,P##t4,P##t5,P##t6,P##t7;

#define BURST(P, OLO, OHI, TLO, THI)                                        \
    asm volatile(                                                           \
        "global_load_dwordx4 %0,  %[olo], off\n\t"                          \
        "global_load_dwordx4 %1,  %[olo], off offset:1024\n\t"              \
        "global_load_dwordx4 %2,  %[olo], off offset:2048\n\t"              \
        "global_load_dwordx4 %3,  %[olo], off offset:3072\n\t"              \
        "global_load_dwordx4 %4,  %[ohi], off\n\t"                          \
        "global_load_dwordx4 %5,  %[ohi], off offset:1024\n\t"              \
        "global_load_dwordx4 %6,  %[ohi], off offset:2048\n\t"              \
        "global_load_dwordx4 %7,  %[ohi], off offset:3072\n\t"              \
        "global_load_dwordx4 %8,  %[tlo], off\n\t"                          \
        "global_load_dwordx4 %9,  %[tlo], off offset:1024\n\t"              \
        "global_load_dwordx4 %10, %[tlo], off offset:2048\n\t"              \
        "global_load_dwordx4 %11, %[tlo], off offset:3072\n\t"              \
        "global_load_dwordx4 %12, %[thi], off\n\t"                          \
        "global_load_dwordx4 %13, %[thi], off offset:1024\n\t"              \
        "global_load_dwordx4 %14, %[thi], off offset:2048\n\t"              \
        "global_load_dwordx4 %15, %[thi], off offset:3072"                  \
        : "=&v"(P##o0), "=&v"(P##o1), "=&v"(P##o2), "=&v"(P##o3),           \
          "=&v"(P##o4), "=&v"(P##o5), "=&v"(P##o6), "=&v"(P##o7),           \
          "=&v"(P##t0), "=&v"(P##t1), "=&v"(P##t2), "=&v"(P##t3),           \
          "=&v"(P##t4), "=&v"(P##t5), "=&v"(P##t6), "=&v"(P##t7)            \
        : [olo] "v"(OLO), [ohi] "v"(OHI), [tlo] "v"(TLO), [thi] "v"(THI)    \
        : "memory");

// Counted waits. sched_barrier(0) right after: hipcc hoists register-only
// ops past inline-asm waitcnt despite "memory" (rule 18).
#define WAITV16 asm volatile("s_waitcnt vmcnt(16)" ::: "memory"); \
                __builtin_amdgcn_sched_barrier(0);
#define WAITV0  asm volatile("s_waitcnt vmcnt(0)"  ::: "memory"); \
                __builtin_amdgcn_sched_barrier(0);

#define ACC(OV, TV)                                                  \
    {                                                                \
        float d0 = OV[0] - TV[0];                                    \
        float d1 = OV[1] - TV[1];                                    \
        float d2 = OV[2] - TV[2];                                    \
        float d3 = OV[3] - TV[3];                                    \
        ssd0 += d0 * d0 + d1 * d1;                                   \
        ssd1 += d2 * d2 + d3 * d3;                                   \
        tmax0 = fmaxf(tmax0, fmaxf(TV[0], TV[1]));                   \
        tmax1 = fmaxf(tmax1, fmaxf(TV[2], TV[3]));                   \
        tmin0 = fminf(tmin0, fminf(TV[0], TV[1]));                   \
        tmin1 = fminf(tmin1, fminf(TV[2], TV[3]));                   \
    }

// Full per-row statistic: accumulate, wave-64 butterfly, add weighted nrmse.
#define ROWSTAT(P, W)                                                       \
    {                                                                       \
        float ssd0 = 0.0f, ssd1 = 0.0f;                                     \
        float tmax0 = -INFINITY, tmax1 = -INFINITY;                         \
        float tmin0 =  INFINITY, tmin1 =  INFINITY;                         \
        ACC(P##o0, P##t0) ACC(P##o1, P##t1) ACC(P##o2, P##t2)               \
        ACC(P##o3, P##t3) ACC(P##o4, P##t4) ACC(P##o5, P##t5)               \
        ACC(P##o6, P##t6) ACC(P##o7, P##t7)                                 \
        float ssd  = ssd0 + ssd1;                                           \
        float tmax = fmaxf(tmax0, tmax1);                                   \
        float tmin = fminf(tmin0, tmin1);                                   \
        _Pragma("unroll")                                                   \
        for (int off = 32; off > 0; off >>= 1) {                            \
            ssd  += __shfl_xor(ssd, off, 64);                               \
            tmax  = fmaxf(tmax, __shfl_xor(tmax, off, 64));                 \
            tmin  = fminf(tmin, __shfl_xor(tmin, off, 64));                 \
        }                                                                   \
        local += (W) * sqrtf(ssd * (1.0f / (float)N_ELEM)) / (tmax - tmin); \
    }

__global__ __launch_bounds__(BLOCK, 3)   // cap VGPR so 3 blocks/CU resident
void wnrmse_stage1(const float* __restrict__ o1, const float* __restrict__ t1,
                   const float* __restrict__ o2, const float* __restrict__ t2,
                   const float* __restrict__ o3, const float* __restrict__ t3,
                   float* __restrict__ partial)
{
    const int tid  = threadIdx.x;
    const int wave = tid >> 6;
    const int lane = tid & 63;
    const int gw   = blockIdx.x * (BLOCK / 64) + wave;   // 0..3071

    struct Addr { const float* olo; const float* ohi;
                  const float* tlo; const float* thi; float w; };
    auto decode = [&](int task, Addr& a) {
        const int pair = task >> 12;          // wave-uniform
        const int row  = task & (BATCH - 1);
        const float* ob = (pair == 0) ? o1 : ((pair == 1) ? o2 : o3);
        const float* tb = (pair == 0) ? t1 : ((pair == 1) ? t2 : t3);
        a.olo = ob + (size_t)row * N_ELEM + lane * 4;
        a.ohi = a.olo + 1024;                 // +4096 bytes
        a.tlo = tb + (size_t)row * N_ELEM + lane * 4;
        a.thi = a.tlo + 1024;
        a.w   = (pair == 0) ? 0.50f : 0.25f;
    };

    float local = 0.0f;
    DECL_SET(A) DECL_SET(B) DECL_SET(C) DECL_SET(D)

    Addr k0, k1, k2, k3;
    decode(gw,             k0);
    decode(gw + WAVES,     k1);
    BURST(A, k0.olo, k0.ohi, k0.tlo, k0.thi)        // 16 outstanding
    BURST(B, k1.olo, k1.ohi, k1.tlo, k1.thi)        // 32 outstanding

    WAITV16                                          // task0 data ready
    ROWSTAT(A, k0.w)
    decode(gw + 2 * WAVES, k2);
    BURST(C, k2.olo, k2.ohi, k2.tlo, k2.thi)        // back to 32 outstanding

    WAITV16                                          // task1 ready
    ROWSTAT(B, k1.w)
    decode(gw + 3 * WAVES, k3);
    BURST(D, k3.olo, k3.ohi, k3.tlo, k3.thi)

    WAITV16                                          // task2 ready
    ROWSTAT(C, k2.w)

    WAITV0                                           // last task
    ROWSTAT(D, k3.w)

    // Per-block combine, one plain store per block.
    __shared__ float s_part[BLOCK / 64];
    if (lane == 0) s_part[wave] = local;
    __syncthreads();
    if (tid == 0) {
        partial[blockIdx.x] = s_part[0] + s_part[1] + s_part[2] + s_part[3];
    }
}

// Stage 2: one block reduces GRID1 partials and writes the final scalar.
__global__ __launch_bounds__(BLOCK)
void wnrmse_stage2(const float* __restrict__ partial, float* __restrict__ out)
{
    const int tid = threadIdx.x;
    float s = 0.0f;
    for (int i = tid; i < GRID1; i += BLOCK) s += partial[i];

#pragma unroll
    for (int off = 32; off > 0; off >>= 1) s += __shfl_xor(s, off, 64);

    __shared__ float s_part[BLOCK / 64];
    const int wave = tid >> 6;
    const int lane = tid & 63;
    if (lane == 0) s_part[wave] = s;
    __syncthreads();
    if (tid == 0) {
        float tot = s_part[0] + s_part[1] + s_part[2] + s_part[3];
        out[0] = tot * (1.0f / (float)BATCH);
    }
}

extern "C" void kernel_launch(void* const* d_in, const int* in_sizes, int n_in,
                              void* d_out, int out_size, void* d_ws, size_t ws_size,
                              hipStream_t stream) {
    const float* o1 = (const float*)d_in[0];
    const float* t1 = (const float*)d_in[1];
    const float* o2 = (const float*)d_in[2];
    const float* t2 = (const float*)d_in[3];
    const float* o3 = (const float*)d_in[4];
    const float* t3 = (const float*)d_in[5];
    float* out     = (float*)d_out;
    float* partial = (float*)d_ws;    // GRID1 floats = 3 KiB, fully overwritten

    wnrmse_stage1<<<GRID1, BLOCK, 0, stream>>>(o1, t1, o2, t2, o3, t3, partial);
    wnrmse_stage2<<<1, BLOCK, 0, stream>>>(partial, out);
}